// Round 12
// baseline (422.918 us; speedup 1.0000x reference)
//
#include <hip/hip_runtime.h>
#include <hip/hip_fp16.h>

#define CIN   64
#define COUT  128
#define HIN   128
#define WIN   128
#define HOUT  126
#define WOUT  126
#define HP    63
#define WP    63
#define NB    32
#define NG    16
#define EPS   1e-5f
#define KTOT  576            // 9 * 64, k = (kh*3+kw)*64 + ci

// LDS x-tile (f16), per buffer: [4 rows][66 cols][cell = 32 ci f16 (64B) + 16B pad = 80B]
#define CELLB 80
#define NCOLT 66
#define ROWB  (NCOLT * CELLB)   // 5280
#define XHALF (4 * ROWB)        // 21120 per buffer
#define NTILE 126               // rp*2 + ct

// tiled y: [b][co][chunk(126)][row(2)][col(64)] ; chunk = 128 floats (512B)
#define YCHUNK 128
#define YPLANE (126 * YCHUNK)   // 16128 floats per (b,co)

typedef __attribute__((ext_vector_type(8))) _Float16 half8;
typedef __attribute__((ext_vector_type(4))) float f32x4;

// ---- weight prep: cw[co][ci][3][3] f32 -> wt[co][k] f16 hi/lo, k=(kh*3+kw)*64+ci
__global__ __launch_bounds__(256) void wprep_kernel(
    const float* __restrict__ cw, ushort* __restrict__ wh, ushort* __restrict__ wl)
{
    int idx = blockIdx.x * 256 + threadIdx.x;
    if (idx >= COUT * KTOT) return;
    int co = idx / KTOT, k = idx - co * KTOT;
    int khw = k >> 6, ci = k & 63;
    float v = cw[(co * CIN + ci) * 9 + khw];
    __half h = __float2half(v);
    __half l = __float2half(v - __half2float(h));
    wh[idx] = __half_as_ushort(h);
    wl[idx] = __half_as_ushort(l);
}

// ---- conv implicit GEMM: block = 2 rows x 64 cols x 128 couts, 8 waves.
// wave = 2 cout-tiles (32 couts) x 4 spatial-tiles (2 rows x 32 cols):
// per khw 4 LDS B-reads + 4 L2 A-loads for 16 MFMAs (half r10's LDS traffic).
__global__ __launch_bounds__(512, 4) void conv_mfma_kernel(
    const float* __restrict__ x, const ushort* __restrict__ wt_hi,
    const ushort* __restrict__ wt_lo, const float* __restrict__ cb,
    float* __restrict__ y, float* __restrict__ partials)
{
    __shared__ char xs[2 * XHALF];
    __shared__ float wred[8][2][4][2];

    const int tid = threadIdx.x;
    // XCD swizzle: 4032 blocks = 8 XCDs x 504; each XCD gets 4 whole images
    const int bid = blockIdx.x;
    const int w   = (bid & 7) * 504 + (bid >> 3);
    const int b   = w / 126;
    const int r   = w - b * 126;
    const int rp  = r >> 1;            // 0..62 row pair
    const int ct  = r & 1;             // col tile
    const int r0x = rp * 2;            // first x row needed (<=124; rows always valid)

    const int l = tid & 63, wid = tid >> 6;
    const int wg = wid >> 1;           // cout group of 32 (0..3)
    const int h  = wid & 1;            // col half (32 cols)
    const int l15 = l & 15, lhi = l >> 4;

    f32x4 acc[2][4];                   // [mt][nt] ; nt = nr*2 + nc
#pragma unroll
    for (int mt = 0; mt < 2; ++mt)
#pragma unroll
        for (int nt = 0; nt < 4; ++nt)
            acc[mt][nt] = (f32x4){0.f, 0.f, 0.f, 0.f};

    const float* xb = x + (size_t)b * (CIN * HIN * WIN);

    // main staging task (exactly 512): c4 = col quad (0..15), rr = row, cig = 4-ci group
    const int c4 = tid & 15, rr = (tid >> 4) & 3, cig = tid >> 6;
    const float* xmain = xb + (size_t)(cig * 4) * (HIN * WIN)
                       + (r0x + rr) * WIN + ct * 64 + c4 * 4;   // always in-bounds
    char* wmain = xs + rr * ROWB + (c4 * 4) * CELLB + cig * 8;

#define LOADMAIN(cip, f)                                                   \
    {                                                                      \
        _Pragma("unroll")                                                  \
        for (int q = 0; q < 4; ++q)                                        \
            f[q] = *(const f32x4*)(xmain + (size_t)((cip) * 32 + q) * (HIN * WIN)); \
    }

#define WRITEMAIN(f, buf)                                                  \
    {                                                                      \
        _Pragma("unroll")                                                  \
        for (int j = 0; j < 4; ++j) {                                      \
            ushort h0 = __half_as_ushort(__float2half(f[0][j]));           \
            ushort h1 = __half_as_ushort(__float2half(f[1][j]));           \
            ushort h2 = __half_as_ushort(__float2half(f[2][j]));           \
            ushort h3 = __half_as_ushort(__float2half(f[3][j]));           \
            uint2 hp;                                                      \
            hp.x = (unsigned)h0 | ((unsigned)h1 << 16);                    \
            hp.y = (unsigned)h2 | ((unsigned)h3 << 16);                    \
            *(uint2*)(wmain + (buf) * XHALF + j * CELLB) = hp;             \
        }                                                                  \
    }

    // tail: halo cols 64,65 (global cols ct*64+64/65; OOB for ct=1 -> zeros)
#define TAIL(cip, buf)                                                     \
    if (tid < 32) {                                                        \
        int trr = tid & 3, tcig = tid >> 2;                                \
        float2 g[4];                                                       \
        _Pragma("unroll")                                                  \
        for (int q = 0; q < 4; ++q) {                                      \
            if (ct == 0)                                                   \
                g[q] = *(const float2*)(xb                                 \
                      + (size_t)((cip) * 32 + tcig * 4 + q) * (HIN * WIN)  \
                      + (r0x + trr) * WIN + 64);                           \
            else g[q] = make_float2(0.f, 0.f);                             \
        }                                                                  \
        _Pragma("unroll")                                                  \
        for (int j = 0; j < 2; ++j) {                                      \
            float v0 = j ? g[0].y : g[0].x, v1 = j ? g[1].y : g[1].x;      \
            float v2 = j ? g[2].y : g[2].x, v3 = j ? g[3].y : g[3].x;      \
            uint2 hp;                                                      \
            hp.x = (unsigned)__half_as_ushort(__float2half(v0))            \
                 | ((unsigned)__half_as_ushort(__float2half(v1)) << 16);   \
            hp.y = (unsigned)__half_as_ushort(__float2half(v2))            \
                 | ((unsigned)__half_as_ushort(__float2half(v3)) << 16);   \
            *(uint2*)(xs + (buf) * XHALF + trr * ROWB + (64 + j) * CELLB   \
                      + tcig * 8) = hp;                                    \
        }                                                                  \
    }

    // A-fragment base (cout tiles wg*32 + mt*16)
    const ushort* wbh = wt_hi + (size_t)(wg * 32 + l15) * KTOT + lhi * 8;
    const ushort* wbl = wt_lo + (size_t)(wg * 32 + l15) * KTOT + lhi * 8;
    const char* pb = xs + l15 * CELLB + lhi * 16;

#define COMPUTE(buf, cip)                                                  \
    {                                                                      \
        _Pragma("unroll")                                                  \
        for (int khw = 0; khw < 9; ++khw) {                                \
            const int kh = khw / 3, kw = khw - kh * 3;                     \
            half8 ah[2], al[2];                                            \
            _Pragma("unroll")                                              \
            for (int mt = 0; mt < 2; ++mt) {                               \
                ah[mt] = *(const half8*)(wbh + mt * 16 * KTOT + khw * 64 + (cip) * 32); \
                al[mt] = *(const half8*)(wbl + mt * 16 * KTOT + khw * 64 + (cip) * 32); \
            }                                                              \
            half8 bv[4];                                                   \
            _Pragma("unroll")                                              \
            for (int nt = 0; nt < 4; ++nt)                                 \
                bv[nt] = *(const half8*)(pb + (buf) * XHALF                \
                        + ((nt >> 1) + kh) * ROWB                          \
                        + (h * 32 + (nt & 1) * 16 + kw) * CELLB);          \
            _Pragma("unroll")                                              \
            for (int mt = 0; mt < 2; ++mt)                                 \
                _Pragma("unroll")                                          \
                for (int nt = 0; nt < 4; ++nt)                             \
                    acc[mt][nt] = __builtin_amdgcn_mfma_f32_16x16x32_f16(  \
                        ah[mt], bv[nt], acc[mt][nt], 0, 0, 0);             \
            _Pragma("unroll")                                              \
            for (int mt = 0; mt < 2; ++mt)                                 \
                _Pragma("unroll")                                          \
                for (int nt = 0; nt < 4; ++nt)                             \
                    acc[mt][nt] = __builtin_amdgcn_mfma_f32_16x16x32_f16(  \
                        al[mt], bv[nt], acc[mt][nt], 0, 0, 0);             \
        }                                                                  \
    }

    // ---- prologue: stage chunk 0 into buffer 0
    {
        f32x4 f0[4];
        LOADMAIN(0, f0);
        WRITEMAIN(f0, 0);
        TAIL(0, 0);
    }
    __syncthreads();

    // ---- pipelined: issue chunk-1 loads, compute chunk 0, write chunk 1
    {
        f32x4 f1[4];
        LOADMAIN(1, f1);
        __builtin_amdgcn_sched_barrier(0);   // pin loads above the compute
        COMPUTE(0, 0);
        WRITEMAIN(f1, 1);                    // vmcnt wait inserted by compiler
        TAIL(1, 1);
    }
    __syncthreads();
    COMPUTE(1, 1);

#undef LOADMAIN
#undef WRITEMAIN
#undef TAIL
#undef COMPUTE

    // ---- epilogue: bias, store y, group partials
    float* ybase = y + (size_t)b * COUT * YPLANE
                 + (size_t)((rp * 2 + ct) * YCHUNK) + h * 32 + l15;

#pragma unroll
    for (int mt = 0; mt < 2; ++mt) {
        float s1 = 0.f, s2 = 0.f;
#pragma unroll
        for (int r2 = 0; r2 < 4; ++r2) {
            int co = wg * 32 + mt * 16 + lhi * 4 + r2;
            float bias = cb[co];
            float* yp = ybase + (size_t)co * YPLANE;
#pragma unroll
            for (int nt = 0; nt < 4; ++nt) {
                float v = acc[mt][nt][r2] + bias;
                yp[(nt >> 1) * 64 + (nt & 1) * 16] = v;
                if (ct * 64 + h * 32 + (nt & 1) * 16 + l15 < WOUT) {
                    s1 += v; s2 += v * v;
                }
            }
        }
        // reduce over the 16 l15 lanes (same lhi => same couts)
#pragma unroll
        for (int d = 1; d < 16; d <<= 1) {
            s1 += __shfl_xor(s1, d);
            s2 += __shfl_xor(s2, d);
        }
        if (l15 == 0) {
            wred[wid][mt][lhi][0] = s1;
            wred[wid][mt][lhi][1] = s2;
        }
    }
    __syncthreads();

    if (tid < NG) {
        int g = tid;                       // couts [8g, 8g+8)
        int wg2 = g >> 2, mt = (g >> 1) & 1, lh0 = (g & 1) * 2;
        float t1 = 0.f, t2 = 0.f;
#pragma unroll
        for (int hh = 0; hh < 2; ++hh)
#pragma unroll
            for (int dl = 0; dl < 2; ++dl) {
                t1 += wred[wg2 * 2 + hh][mt][lh0 + dl][0];
                t2 += wred[wg2 * 2 + hh][mt][lh0 + dl][1];
            }
        size_t pidx = (((size_t)b * NG + g) * NTILE + (rp * 2 + ct)) * 2;
        partials[pidx + 0] = t1;
        partials[pidx + 1] = t2;
    }
}

__global__ void stats_kernel(const float* __restrict__ partials,
                             float* __restrict__ stats)
{
    int t = blockIdx.x * blockDim.x + threadIdx.x;
    if (t >= NB * NG) return;
    float s1 = 0.f, s2 = 0.f;
    for (int j = 0; j < NTILE; ++j) {
        s1 += partials[((size_t)t * NTILE + j) * 2 + 0];
        s2 += partials[((size_t)t * NTILE + j) * 2 + 1];
    }
    const float N = 8.f * HOUT * WOUT;
    float mean = s1 / N;
    float var = s2 / N - mean * mean;
    stats[t * 2 + 0] = mean;
    stats[t * 2 + 1] = rsqrtf(var + EPS);
}

__global__ __launch_bounds__(256) void pool_kernel(
    const float* __restrict__ y, const float* __restrict__ stats,
    const float* __restrict__ gw, const float* __restrict__ gb,
    const float* __restrict__ sc, float* __restrict__ out)
{
    int idx = blockIdx.x * 256 + threadIdx.x;
    if (idx >= NB * COUT * HP * WP) return;
    int owp = idx % WP;
    int t = idx / WP;
    int ohp = t % HP; t /= HP;
    int c = t % COUT;
    int b = t / COUT;
    int g = c >> 3;

    float mean = stats[(b * NG + g) * 2 + 0];
    float rstd = stats[(b * NG + g) * 2 + 1];
    float ga = rstd * gw[c] * sc[c];
    float gbb = (gb[c] - mean * rstd * gw[c]) * sc[c];

    // tiled y: chunk = ohp*2 + (owp>>5); rows (0,1) of chunk; col = (2*owp)&63
    int ct = owp >> 5, col = (2 * owp) & 63;
    const float* yp = y + (size_t)(b * COUT + c) * YPLANE
                    + (ohp * 2 + ct) * YCHUNK + col;
    float2 r0 = *reinterpret_cast<const float2*>(yp);
    float2 r1 = *reinterpret_cast<const float2*>(yp + 64);
    float v0 = fmaf(r0.x, ga, gbb);
    float v1 = fmaf(r0.y, ga, gbb);
    float v2 = fmaf(r1.x, ga, gbb);
    float v3 = fmaf(r1.y, ga, gbb);
    float m = fmaxf(fmaxf(v0, v1), fmaxf(v2, v3));
    out[idx] = fminf(fmaxf(m, 0.f), 1.f);
}

extern "C" void kernel_launch(void* const* d_in, const int* in_sizes, int n_in,
                              void* d_out, int out_size, void* d_ws, size_t ws_size,
                              hipStream_t stream)
{
    const float* x  = (const float*)d_in[0];
    const float* cw = (const float*)d_in[1];
    const float* cbias = (const float*)d_in[2];
    const float* gw = (const float*)d_in[3];
    const float* gb = (const float*)d_in[4];
    const float* sc = (const float*)d_in[5];
    float* out = (float*)d_out;

    // ws: y 264,241,152 B + partials 1,032,192 + stats 4,096 + weights 294,912
    //   = 265,572,352 B = 253.3 MiB < 256 MiB
    const size_t YSZ = (size_t)NB * COUT * YPLANE;               // 66,060,288 f32
    float* y        = (float*)d_ws;
    float* partials = y + YSZ;                                   // 32*16*126*2 f32
    float* stats    = partials + (size_t)NB * NG * NTILE * 2;    // 1024 f32
    ushort* wh      = (ushort*)(stats + 1024);                   // 128*576 f16
    ushort* wl      = wh + (size_t)COUT * KTOT;

    hipLaunchKernelGGL(wprep_kernel, dim3((COUT * KTOT + 255) / 256), dim3(256),
                       0, stream, cw, wh, wl);

    hipLaunchKernelGGL(conv_mfma_kernel, dim3(4032), dim3(512), 0, stream,
                       x, wh, wl, cbias, y, partials);

    hipLaunchKernelGGL(stats_kernel, dim3(2), dim3(256), 0, stream,
                       partials, stats);

    int total = NB * COUT * HP * WP;
    hipLaunchKernelGGL(pool_kernel, dim3((total + 255) / 256), dim3(256), 0, stream,
                       y, stats, gw, gb, sc, out);
}

// Round 13
// 294.327 us; speedup vs baseline: 1.4369x; 1.4369x over previous
//
#include <hip/hip_runtime.h>
#include <hip/hip_fp16.h>

#define CIN   64
#define COUT  128
#define HIN   128
#define WIN   128
#define HOUT  126
#define WOUT  126
#define HP    63
#define WP    63
#define NB    32
#define NG    16
#define EPS   1e-5f
#define KTOT  576            // 9 * 64, k = (kh*3+kw)*64 + ci

// LDS x-tile (f16), per buffer: [4 rows][34 cols][cell = 32 ci f16 (64B) + 16B pad = 80B]
#define CELLB 80
#define NCOLT 34
#define ROWB  (NCOLT * CELLB)   // 2720
#define XHALF (4 * ROWB)        // 10880 per buffer
#define NTILE 252               // rp*4 + ct

// tiled y: [b][co][chunk(126)][row(2)][col(64)] ; chunk = 128 floats (512B)
#define YCHUNK 128
#define YPLANE (126 * YCHUNK)   // 16128 floats per (b,co)

typedef __attribute__((ext_vector_type(8))) _Float16 half8;
typedef __attribute__((ext_vector_type(4))) float f32x4;

// ---- weight prep: cw[co][ci][3][3] f32 -> wt[co][k] f16, k=(kh*3+kw)*64+ci
__global__ __launch_bounds__(256) void wprep_kernel(
    const float* __restrict__ cw, ushort* __restrict__ wt)
{
    int idx = blockIdx.x * 256 + threadIdx.x;
    if (idx >= COUT * KTOT) return;
    int co = idx / KTOT, k = idx - co * KTOT;
    int khw = k >> 6, ci = k & 63;
    float v = cw[(co * CIN + ci) * 9 + khw];
    wt[idx] = __half_as_ushort(__float2half(v));
}

// ---- conv implicit GEMM: block = 2 rows x 32 cols x 128 couts, 4 waves.
// wave = 2 cout-tiles (32 couts) x (2 rows x 2 col16); single f16 term;
// A-frags for all 9 khw preloaded per ci-chunk (one burst, 72 VGPR).
__global__ __launch_bounds__(256, 3) void conv_mfma_kernel(
    const float* __restrict__ x, const ushort* __restrict__ wt,
    const float* __restrict__ cb, float* __restrict__ y,
    float* __restrict__ partials)
{
    __shared__ char xs[2 * XHALF];

    const int tid = threadIdx.x;
    // XCD swizzle: 8064 blocks = 8 XCDs x 1008; each XCD gets 4 whole images
    const int bid = blockIdx.x;
    const int w   = (bid & 7) * 1008 + (bid >> 3);
    const int b   = w / 252;
    const int r   = w - b * 252;
    const int rp  = r >> 2;            // 0..62 row pair
    const int ct  = r & 3;             // 32-col tile
    const int r0x = rp * 2;            // first x row needed (<=124; rows always valid)

    const int l = tid & 63, wg = tid >> 6;    // wg: cout group of 32
    const int l15 = l & 15, lhi = l >> 4;

    f32x4 acc[2][4];                   // [mt][nt]; nt = nr*2 + nc
#pragma unroll
    for (int mt = 0; mt < 2; ++mt)
#pragma unroll
        for (int nt = 0; nt < 4; ++nt)
            acc[mt][nt] = (f32x4){0.f, 0.f, 0.f, 0.f};

    const float* xb = x + (size_t)b * (CIN * HIN * WIN);

    // main staging task (exactly 256): c4 = col quad (0..7), rr = row, cig = 4-ci group
    const int c4 = tid & 7, rr = (tid >> 3) & 3, cig = tid >> 5;
    const float* xmain = xb + (size_t)(cig * 4) * (HIN * WIN)
                       + (r0x + rr) * WIN + ct * 32 + c4 * 4;   // cols <=127, in-bounds
    char* wmain = xs + rr * ROWB + (c4 * 4) * CELLB + cig * 8;

#define LOADMAIN(cip, f)                                                   \
    {                                                                      \
        _Pragma("unroll")                                                  \
        for (int q = 0; q < 4; ++q)                                        \
            f[q] = *(const f32x4*)(xmain + (size_t)((cip) * 32 + q) * (HIN * WIN)); \
    }

#define WRITEMAIN(f, buf)                                                  \
    {                                                                      \
        _Pragma("unroll")                                                  \
        for (int j = 0; j < 4; ++j) {                                      \
            ushort h0 = __half_as_ushort(__float2half(f[0][j]));           \
            ushort h1 = __half_as_ushort(__float2half(f[1][j]));           \
            ushort h2 = __half_as_ushort(__float2half(f[2][j]));           \
            ushort h3 = __half_as_ushort(__float2half(f[3][j]));           \
            uint2 hp;                                                      \
            hp.x = (unsigned)h0 | ((unsigned)h1 << 16);                    \
            hp.y = (unsigned)h2 | ((unsigned)h3 << 16);                    \
            *(uint2*)(wmain + (buf) * XHALF + j * CELLB) = hp;             \
        }                                                                  \
    }

    // tail: halo cols 32,33 of the tile (global ct*32+32/33; OOB only for ct=3)
#define TAIL(cip, buf)                                                     \
    if (tid < 64) {                                                        \
        int tcol = tid & 1, trr = (tid >> 1) & 3, tcig = tid >> 3;         \
        int gcol = ct * 32 + 32 + tcol;                                    \
        float g[4];                                                        \
        _Pragma("unroll")                                                  \
        for (int q = 0; q < 4; ++q)                                        \
            g[q] = (gcol < WIN)                                            \
                 ? xb[(size_t)((cip) * 32 + tcig * 4 + q) * (HIN * WIN)    \
                      + (r0x + trr) * WIN + gcol]                          \
                 : 0.f;                                                    \
        uint2 hp;                                                          \
        hp.x = (unsigned)__half_as_ushort(__float2half(g[0]))              \
             | ((unsigned)__half_as_ushort(__float2half(g[1])) << 16);     \
        hp.y = (unsigned)__half_as_ushort(__float2half(g[2]))              \
             | ((unsigned)__half_as_ushort(__float2half(g[3])) << 16);     \
        *(uint2*)(xs + (buf) * XHALF + (trr * NCOLT + 32 + tcol) * CELLB   \
                  + tcig * 8) = hp;                                        \
    }

    // A-fragment base (cout tiles wg*32 + mt*16), k = khw*64 + cip*32 + lhi*8 + j
    const ushort* wbase = wt + (size_t)(wg * 32 + l15) * KTOT + lhi * 8;
    const char* pb = xs + l15 * CELLB + lhi * 16;

#define COMPUTE(buf, cip)                                                  \
    {                                                                      \
        half8 wfa[2][9];                                                   \
        _Pragma("unroll")                                                  \
        for (int mt = 0; mt < 2; ++mt)                                     \
            _Pragma("unroll")                                              \
            for (int khw = 0; khw < 9; ++khw)                              \
                wfa[mt][khw] = *(const half8*)(wbase + mt * 16 * KTOT      \
                              + khw * 64 + (cip) * 32);                    \
        _Pragma("unroll")                                                  \
        for (int khw = 0; khw < 9; ++khw) {                                \
            const int kh = khw / 3, kw = khw - kh * 3;                     \
            half8 bv[4];                                                   \
            _Pragma("unroll")                                              \
            for (int nt = 0; nt < 4; ++nt)                                 \
                bv[nt] = *(const half8*)(pb + (buf) * XHALF                \
                        + ((nt >> 1) + kh) * ROWB                          \
                        + ((nt & 1) * 16 + kw) * CELLB);                   \
            _Pragma("unroll")                                              \
            for (int nt = 0; nt < 4; ++nt)                                 \
                _Pragma("unroll")                                          \
                for (int mt = 0; mt < 2; ++mt)                             \
                    acc[mt][nt] = __builtin_amdgcn_mfma_f32_16x16x32_f16(  \
                        wfa[mt][khw], bv[nt], acc[mt][nt], 0, 0, 0);       \
        }                                                                  \
    }

    // ---- prologue: stage chunk 0 into buffer 0
    {
        f32x4 f0[4];
        LOADMAIN(0, f0);
        WRITEMAIN(f0, 0);
        TAIL(0, 0);
    }
    __syncthreads();

    // ---- pipelined: issue chunk-1 loads, compute chunk 0, write chunk 1
    {
        f32x4 f1[4];
        LOADMAIN(1, f1);
        __builtin_amdgcn_sched_barrier(0);   // pin loads above the compute
        COMPUTE(0, 0);
        WRITEMAIN(f1, 1);                    // vmcnt wait inserted by compiler
        TAIL(1, 1);
    }
    __syncthreads();
    COMPUTE(1, 1);

#undef LOADMAIN
#undef WRITEMAIN
#undef TAIL
#undef COMPUTE

    // ---- epilogue: bias, store y, per-wave group partials (no extra barrier)
    float* ybase = y + (size_t)b * COUT * YPLANE
                 + (size_t)((rp * 2 + (ct >> 1)) * YCHUNK) + (ct & 1) * 32 + l15;

    float ps1 = 0.f, ps2 = 0.f;        // this lane's half-tile (8 couts) partial
#pragma unroll
    for (int mt = 0; mt < 2; ++mt) {
        float s1 = 0.f, s2 = 0.f;
#pragma unroll
        for (int r2 = 0; r2 < 4; ++r2) {
            int co = wg * 32 + mt * 16 + lhi * 4 + r2;
            float bias = cb[co];
            float* yp = ybase + (size_t)co * YPLANE;
#pragma unroll
            for (int nt = 0; nt < 4; ++nt) {
                float v = acc[mt][nt][r2] + bias;
                yp[(nt >> 1) * 64 + (nt & 1) * 16] = v;
                if (ct * 32 + (nt & 1) * 16 + l15 < WOUT) { s1 += v; s2 += v * v; }
            }
        }
        if (mt == 0) { ps1 = s1; ps2 = s2; }
        else {
            // stash mt results separately via second pass below
        }
        // reduce over 16 l15 lanes
#pragma unroll
        for (int d = 1; d < 16; d <<= 1) {
            s1 += __shfl_xor(s1, d);
            s2 += __shfl_xor(s2, d);
        }
        // combine lhi pairs (0<->1 and 2<->3): lanes 0,16 -> group lo; 32,48 -> hi
        s1 += __shfl_xor(s1, 16);
        s2 += __shfl_xor(s2, 16);
        if (l15 == 0 && (lhi & 1) == 0) {
            int g = wg * 4 + mt * 2 + (lhi >> 1);     // couts [8g, 8g+8)
            size_t pidx = (((size_t)b * NG + g) * NTILE + (rp * 4 + ct)) * 2;
            partials[pidx + 0] = s1;
            partials[pidx + 1] = s2;
        }
    }
    (void)ps1; (void)ps2;
}

__global__ void stats_kernel(const float* __restrict__ partials,
                             float* __restrict__ stats)
{
    int t = blockIdx.x * blockDim.x + threadIdx.x;
    if (t >= NB * NG) return;
    float s1 = 0.f, s2 = 0.f;
    for (int j = 0; j < NTILE; ++j) {
        s1 += partials[((size_t)t * NTILE + j) * 2 + 0];
        s2 += partials[((size_t)t * NTILE + j) * 2 + 1];
    }
    const float N = 8.f * HOUT * WOUT;
    float mean = s1 / N;
    float var = s2 / N - mean * mean;
    stats[t * 2 + 0] = mean;
    stats[t * 2 + 1] = rsqrtf(var + EPS);
}

__global__ __launch_bounds__(256) void pool_kernel(
    const float* __restrict__ y, const float* __restrict__ stats,
    const float* __restrict__ gw, const float* __restrict__ gb,
    const float* __restrict__ sc, float* __restrict__ out)
{
    int idx = blockIdx.x * 256 + threadIdx.x;
    if (idx >= NB * COUT * HP * WP) return;
    int owp = idx % WP;
    int t = idx / WP;
    int ohp = t % HP; t /= HP;
    int c = t % COUT;
    int b = t / COUT;
    int g = c >> 3;

    float mean = stats[(b * NG + g) * 2 + 0];
    float rstd = stats[(b * NG + g) * 2 + 1];
    float ga = rstd * gw[c] * sc[c];
    float gbb = (gb[c] - mean * rstd * gw[c]) * sc[c];

    // tiled y: chunk = ohp*2 + (owp>>5); rows (0,1) of chunk; col = (2*owp)&63
    int ct = owp >> 5, col = (2 * owp) & 63;
    const float* yp = y + (size_t)(b * COUT + c) * YPLANE
                    + (ohp * 2 + ct) * YCHUNK + col;
    float2 r0 = *reinterpret_cast<const float2*>(yp);
    float2 r1 = *reinterpret_cast<const float2*>(yp + 64);
    float v0 = fmaf(r0.x, ga, gbb);
    float v1 = fmaf(r0.y, ga, gbb);
    float v2 = fmaf(r1.x, ga, gbb);
    float v3 = fmaf(r1.y, ga, gbb);
    float m = fmaxf(fmaxf(v0, v1), fmaxf(v2, v3));
    out[idx] = fminf(fmaxf(m, 0.f), 1.f);
}

extern "C" void kernel_launch(void* const* d_in, const int* in_sizes, int n_in,
                              void* d_out, int out_size, void* d_ws, size_t ws_size,
                              hipStream_t stream)
{
    const float* x  = (const float*)d_in[0];
    const float* cw = (const float*)d_in[1];
    const float* cbias = (const float*)d_in[2];
    const float* gw = (const float*)d_in[3];
    const float* gb = (const float*)d_in[4];
    const float* sc = (const float*)d_in[5];
    float* out = (float*)d_out;

    // ws: y 264,241,152 B + partials 2,064,384 B + stats 4,096 + weights 147,456
    //   = 266.5 MB < 268.4 MB (256 MiB)
    const size_t YSZ = (size_t)NB * COUT * YPLANE;               // 66,060,288 f32
    float* y        = (float*)d_ws;
    float* partials = y + YSZ;                                   // 32*16*252*2 f32
    float* stats    = partials + (size_t)NB * NG * NTILE * 2;    // 1024 f32
    ushort* wt      = (ushort*)(stats + 1024);                   // 128*576 f16

    hipLaunchKernelGGL(wprep_kernel, dim3((COUT * KTOT + 255) / 256), dim3(256),
                       0, stream, cw, wt);

    hipLaunchKernelGGL(conv_mfma_kernel, dim3(8064), dim3(256), 0, stream,
                       x, wt, cbias, y, partials);

    hipLaunchKernelGGL(stats_kernel, dim3(2), dim3(256), 0, stream,
                       partials, stats);

    int total = NB * COUT * HP * WP;
    hipLaunchKernelGGL(pool_kernel, dim3((total + 255) / 256), dim3(256), 0, stream,
                       y, stats, gw, gb, sc, out);
}